// Round 11
// baseline (320.121 us; speedup 1.0000x reference)
//
#include <hip/hip_runtime.h>
#include <hip/hip_bf16.h>
#include <type_traits>

// Problem constants
constexpr int SEQ = 4096;
constexpr int DMODEL = 1024;
constexpr int NH = 16;
constexpr int DKH = 64;          // head dim
constexpr float SCALE = 0.125f;  // 1/sqrt(64)
// fold log2(e) into Q scale so softmax uses raw v_exp_f32 (2^x).
constexpr float SCALE2 = 0.125f * 1.4426950408889634f;

typedef __bf16 bf16x8 __attribute__((ext_vector_type(8)));
typedef __bf16 bf16x4 __attribute__((ext_vector_type(4)));
typedef float f32x4 __attribute__((ext_vector_type(4)));
typedef float f32x16 __attribute__((ext_vector_type(16)));
typedef unsigned int u32x4 __attribute__((ext_vector_type(4)));
union W8 { u32x4 u; bf16x8 v; };

__device__ inline void store_c(__hip_bfloat16* p, float v) { *p = __float2bfloat16(v); }
__device__ inline void store_c(float* p, float v) { *p = v; }

typedef const void __attribute__((address_space(1)))* gas_ptr;
typedef void __attribute__((address_space(3)))* las_ptr;
__device__ inline void load_lds_16B(const void* g, void* l) {
  __builtin_amdgcn_global_load_lds((gas_ptr)g, (las_ptr)l, 16, 0, 0);
}

// pack two f32 -> one u32 holding 2 bf16 (compiler emits cvt_pk).
__device__ inline unsigned pack2(float a, float b) {
  union { __bf16 h[2]; unsigned u; } p;
  p.h[0] = (__bf16)a; p.h[1] = (__bf16)b;
  return p.u;
}

// XOR-swizzled [64][64] bf16 LDS tile accessors (16B granularity, T2 pattern).
__device__ inline void st8(__hip_bfloat16* buf, int row, int col, bf16x8 v) {
  *(bf16x8*)(buf + row * 64 + (col ^ ((row & 7) << 3))) = v;
}
__device__ inline bf16x8 ld8(const __hip_bfloat16* buf, int row, int col) {
  return *(const bf16x8*)(buf + row * 64 + (col ^ ((row & 7) << 3)));
}

// ---------------------------------------------------------------------------
// Fused fp32 -> bf16 conversion for all 7 tensors (1 launch instead of 7).
// ---------------------------------------------------------------------------
__global__ __launch_bounds__(256)
void cvt_all(const float* __restrict__ q, const float* __restrict__ k,
             const float* __restrict__ v, const float* __restrict__ wq,
             const float* __restrict__ wk, const float* __restrict__ wv,
             const float* __restrict__ wo,
             __bf16* __restrict__ Xq, __bf16* __restrict__ Xk,
             __bf16* __restrict__ Xv, __bf16* __restrict__ Wqb,
             __bf16* __restrict__ Wkb, __bf16* __restrict__ Wvb,
             __bf16* __restrict__ Wob) {
  const int b = blockIdx.x;
  const float* src; __bf16* dst; size_t base;
  if      (b < 2048) { src = q;  dst = Xq;  base = b; }
  else if (b < 4096) { src = k;  dst = Xk;  base = b - 2048; }
  else if (b < 6144) { src = v;  dst = Xv;  base = b - 4096; }
  else if (b < 6656) { src = wq; dst = Wqb; base = b - 6144; }
  else if (b < 7168) { src = wk; dst = Wkb; base = b - 6656; }
  else if (b < 7680) { src = wv; dst = Wvb; base = b - 7168; }
  else               { src = wo; dst = Wob; base = b - 7680; }
  const size_t i = (base * 256 + threadIdx.x) * 8;
  const float4 a = *(const float4*)(src + i);
  const float4 c = *(const float4*)(src + i + 4);
  bf16x8 r = {(__bf16)a.x, (__bf16)a.y, (__bf16)a.z, (__bf16)a.w,
              (__bf16)c.x, (__bf16)c.y, (__bf16)c.z, (__bf16)c.w};
  *(bf16x8*)(dst + i) = r;
}

// ---------------------------------------------------------------------------
// Final-projection GEMM: BM=128, BN=64, BK=64. Grid MUST be (16,32).
// XCD-clustered decode (T1). Unchanged.
// ---------------------------------------------------------------------------
constexpr int BK = 64;

template <typename TC, bool TRANS_C>
__global__ __launch_bounds__(256)
void gemm128(const __bf16* __restrict__ A,
             const __bf16* __restrict__ W,
             const float* __restrict__ bias,
             TC* __restrict__ C,
             float out_scale) {
  __shared__ alignas(16) __bf16 As[128][64];  // 16 KB
  __shared__ alignas(16) __bf16 Ws[64][64];   // 8 KB

  const int t = threadIdx.x;
  const int lane = t & 63;
  const int w = t >> 6;
  const int wr = w >> 1;
  const int wc = w & 1;
  const int col = lane & 15;
  const int quad = lane >> 4;

  const int L = blockIdx.x + 16 * blockIdx.y;
  const int xcd = L & 7;
  const int c = L >> 3;
  const int m_blk = (xcd * 4 + (c >> 4)) * 128;
  const int n_blk = (c & 15) * 64;

  const int srow = t >> 3;
  const int scol = (t & 7) * 8;

  f32x4 acc[4][2] = {};

  for (int k0 = 0; k0 < DMODEL; k0 += BK) {
    __syncthreads();
    #pragma unroll
    for (int p = 0; p < 4; ++p)
      load_lds_16B(A + (size_t)(m_blk + p * 32 + srow) * DMODEL + k0 + scol,
                   &As[p * 32 + srow][scol]);
    #pragma unroll
    for (int p = 0; p < 2; ++p)
      load_lds_16B(W + (size_t)(n_blk + p * 32 + srow) * DMODEL + k0 + scol,
                   &Ws[p * 32 + srow][scol]);
    __syncthreads();

    #pragma unroll
    for (int kh = 0; kh < BK; kh += 32) {
      bf16x8 af[4], bfr[2];
      #pragma unroll
      for (int at = 0; at < 4; ++at)
        af[at] = *(const bf16x8*)&As[wr * 64 + at * 16 + col][kh + quad * 8];
      #pragma unroll
      for (int bt = 0; bt < 2; ++bt)
        bfr[bt] = *(const bf16x8*)&Ws[wc * 32 + bt * 16 + col][kh + quad * 8];
      #pragma unroll
      for (int at = 0; at < 4; ++at)
        #pragma unroll
        for (int bt = 0; bt < 2; ++bt)
          acc[at][bt] = __builtin_amdgcn_mfma_f32_16x16x32_bf16(
              af[at], bfr[bt], acc[at][bt], 0, 0, 0);
    }
  }

  #pragma unroll
  for (int at = 0; at < 4; ++at) {
    #pragma unroll
    for (int bt = 0; bt < 2; ++bt) {
      const int n = n_blk + wc * 32 + bt * 16 + col;
      const float b = bias[n];
      #pragma unroll
      for (int i = 0; i < 4; ++i) {
        const int m = m_blk + wr * 64 + at * 16 + quad * 4 + i;
        const float v = (acc[at][bt][i] + b) * out_scale;
        if constexpr (TRANS_C) store_c(&C[(size_t)n * SEQ + m], v);
        else                   store_c(&C[(size_t)m * DMODEL + n], v);
      }
    }
  }
}

// ---------------------------------------------------------------------------
// R24: QKV GEMM, 8-phase 256^2 template (T3+T4, linear LDS, no swizzle).
// 512 thr = 8 waves (2M x 4N). R23 BUG FIX: phase quadrant index now selects
// the GLOBAL half. Per-wave output = two 64-row strips (one per A-half) x
// two 32-col strips (one per B-half):
//   A frag row  = MH*128  + wm*64 + fm*16 + col   (phase MH reads ONLY A-half MH)
//   B frag col  = NHF*128 + wn*32 + fn*16 + col   (phase NHF reads ONLY B-half NHF)
// R23's mapping (row = wm*128 + ...) had wm=1 waves reading half 1 in EVERY
// phase -> ph2/ph3 stages overwrote live data (absmax 0.13). Schedule itself
// unchanged:
//   ph0: A1(j+1)->buf1  ph1: B1(j+1)->buf1  ph2: A0(j+2)->buf0
//   ph3: B0(j+2)->buf0  ph4: A1(j+2)->buf0  ph5: B1(j+2)->buf0
//   ph6: A0(j+3)->buf1  ph7: B0(j+3)->buf1
// Slot-freedom (now valid): A0 read ph0,1 / staged ph2; B0 read ph0,2 /
// staged ph3; A1 read ph2,3 / staged ph4; B1 read ph1,3 / staged ph5
// (buf1 mirrored +4). Per-phase lgkmcnt(0) before the trailing barrier makes
// each barrier a cross-wave "ds_reads done" point. vmcnt(4) inside ph3/ph7
// guarantees the next K-tile's 4 half-tiles landed. End-of-range stages
// clamp the SOURCE k only (dest slots + vmcnt counts unchanged).
// ---------------------------------------------------------------------------
__device__ __forceinline__ void stage_half_256(const __bf16* src, __bf16* dst,
                                               int t) {
  const int sr = t >> 3;          // 0..63
  const int sc2 = (t & 7) * 8;    // 0..56
  #pragma unroll
  for (int r = 0; r < 2; ++r)
    load_lds_16B(src + (size_t)(r * 64 + sr) * DMODEL + sc2,
                 dst + (r * 64 + sr) * 64 + sc2);
}

template <int MH, int NHF>
__device__ __forceinline__ void qkv_phase(const __bf16* Asb, const __bf16* Wsb,
                                          int wm, int wn, int col, int quad,
                                          f32x4 (&acc)[8][4],
                                          const __bf16* stage_src,
                                          __bf16* stage_dst, int t,
                                          bool do_vmcnt) {
  bf16x8 af[4][2], bfr[2][2];
  #pragma unroll
  for (int fm = 0; fm < 4; ++fm)
    #pragma unroll
    for (int kh = 0; kh < 2; ++kh)
      af[fm][kh] = *(const bf16x8*)&Asb[(MH * 128 + wm * 64 + fm * 16 + col) * 64 +
                                        kh * 32 + quad * 8];
  #pragma unroll
  for (int fn = 0; fn < 2; ++fn)
    #pragma unroll
    for (int kh = 0; kh < 2; ++kh)
      bfr[fn][kh] = *(const bf16x8*)&Wsb[(NHF * 128 + wn * 32 + fn * 16 + col) * 64 +
                                         kh * 32 + quad * 8];
  stage_half_256(stage_src, stage_dst, t);
  __builtin_amdgcn_s_barrier();
  asm volatile("s_waitcnt lgkmcnt(0)" ::: "memory");
  __builtin_amdgcn_sched_barrier(0);
  __builtin_amdgcn_s_setprio(1);
  #pragma unroll
  for (int kh = 0; kh < 2; ++kh)
    #pragma unroll
    for (int fm = 0; fm < 4; ++fm)
      #pragma unroll
      for (int fn = 0; fn < 2; ++fn)
        acc[MH * 4 + fm][NHF * 2 + fn] = __builtin_amdgcn_mfma_f32_16x16x32_bf16(
            af[fm][kh], bfr[fn][kh], acc[MH * 4 + fm][NHF * 2 + fn], 0, 0, 0);
  __builtin_amdgcn_s_setprio(0);
  if (do_vmcnt) asm volatile("s_waitcnt vmcnt(4)" ::: "memory");
  __builtin_amdgcn_s_barrier();
}

__global__ __launch_bounds__(512, 2)
void gemm_qkv8(const __bf16* __restrict__ Xq, const __bf16* __restrict__ Xk,
               const __bf16* __restrict__ Xv, const __bf16* __restrict__ Wq,
               const __bf16* __restrict__ Wk, const __bf16* __restrict__ Wv,
               const float* __restrict__ bq, const float* __restrict__ bk,
               const float* __restrict__ bv,
               __hip_bfloat16* __restrict__ Cq, __hip_bfloat16* __restrict__ Ck,
               __hip_bfloat16* __restrict__ Cv) {
  __shared__ alignas(16) __bf16 lds_all[4][256 * 64];  // As0 As1 Ws0 Ws1, 128KB
  __bf16* As0 = &lds_all[0][0];
  __bf16* As1 = &lds_all[1][0];
  __bf16* Ws0 = &lds_all[2][0];
  __bf16* Ws1 = &lds_all[3][0];

  const int z = blockIdx.z;
  const __bf16* A = (z == 0) ? Xq : (z == 1) ? Xk : Xv;
  const __bf16* W = (z == 0) ? Wq : (z == 1) ? Wk : Wv;
  const float* bias = (z == 0) ? bq : (z == 1) ? bk : bv;
  __hip_bfloat16* C = (z == 0) ? Cq : (z == 1) ? Ck : Cv;
  const float osc = (z == 0) ? SCALE2 : 1.0f;

  const int t = threadIdx.x;          // 0..511
  const int lane = t & 63;
  const int wave = t >> 6;            // 0..7
  const int wm = wave >> 2;           // 0..1
  const int wn = wave & 3;            // 0..3
  const int col = lane & 15;
  const int quad = lane >> 4;
  const int n_blk = blockIdx.x * 256;
  const int m_blk = blockIdx.y * 256;

  constexpr int NKT = DMODEL / 64;    // 16 K-tiles
  constexpr int NIT = NKT / 2;        // 8 iterations

  auto srcA = [&](int kt, int h) {
    return A + (size_t)(m_blk + h * 128) * DMODEL + kt * 64;
  };
  auto srcB = [&](int kt, int h) {
    return W + (size_t)(n_blk + h * 128) * DMODEL + kt * 64;
  };

  f32x4 acc[8][4] = {};

  // prologue: K0 (4 halves) -> buf0; K1 A0,B0 -> buf1.
  stage_half_256(srcA(0, 0), As0, t);
  stage_half_256(srcA(0, 1), As0 + 128 * 64, t);
  stage_half_256(srcB(0, 0), Ws0, t);
  stage_half_256(srcB(0, 1), Ws0 + 128 * 64, t);
  stage_half_256(srcA(1, 0), As1, t);
  stage_half_256(srcB(1, 0), Ws1, t);
  asm volatile("s_waitcnt vmcnt(4)" ::: "memory");
  __builtin_amdgcn_s_barrier();

  for (int it = 0; it < NIT; ++it) {
    const int j = 2 * it;
    const int kt1 = j + 1;                              // <= 15 always
    const int kt2 = (j + 2 < NKT) ? j + 2 : NKT - 1;    // source clamp only
    const int kt3 = (j + 3 < NKT) ? j + 3 : NKT - 1;
    // phases 0-3: K-tile j from buf0
    qkv_phase<0, 0>(As0, Ws0, wm, wn, col, quad, acc, srcA(kt1, 1), As1 + 128 * 64, t, false);
    qkv_phase<0, 1>(As0, Ws0, wm, wn, col, quad, acc, srcB(kt1, 1), Ws1 + 128 * 64, t, false);
    qkv_phase<1, 0>(As0, Ws0, wm, wn, col, quad, acc, srcA(kt2, 0), As0, t, false);
    qkv_phase<1, 1>(As0, Ws0, wm, wn, col, quad, acc, srcB(kt2, 0), Ws0, t, true);
    // phases 4-7: K-tile j+1 from buf1
    qkv_phase<0, 0>(As1, Ws1, wm, wn, col, quad, acc, srcA(kt2, 1), As0 + 128 * 64, t, false);
    qkv_phase<0, 1>(As1, Ws1, wm, wn, col, quad, acc, srcB(kt2, 1), Ws0 + 128 * 64, t, false);
    qkv_phase<1, 0>(As1, Ws1, wm, wn, col, quad, acc, srcA(kt3, 0), As1, t, false);
    qkv_phase<1, 1>(As1, Ws1, wm, wn, col, quad, acc, srcB(kt3, 0), Ws1, t, true);
  }

  // epilogue: C/D map col=lane&15, row=quad*4+i; strip decomposition:
  // m = (fm>>2)*128 + wm*64 + (fm&3)*16; n = (fn>>1)*128 + wn*32 + (fn&1)*16.
  #pragma unroll
  for (int fm = 0; fm < 8; ++fm)
    #pragma unroll
    for (int fn = 0; fn < 4; ++fn) {
      const int n = n_blk + (fn >> 1) * 128 + wn * 32 + (fn & 1) * 16 + col;
      const float bb = bias[n];
      #pragma unroll
      for (int i = 0; i < 4; ++i) {
        const int m = m_blk + (fm >> 2) * 128 + wm * 64 + (fm & 3) * 16 + quad * 4 + i;
        const float v = (acc[fm][fn][i] + bb) * osc;
        if (z == 2) C[(size_t)n * SEQ + m] = __float2bfloat16(v);
        else        C[(size_t)m * DMODEL + n] = __float2bfloat16(v);
      }
    }
}

// ---------------------------------------------------------------------------
// FALLBACK GEMM — unchanged (only used if ws_size < 40 MB).
// ---------------------------------------------------------------------------
constexpr int LDK = 72;

template <typename TA, typename TC, bool TRANS_C>
__global__ __launch_bounds__(256)
void gemm_tiled(const TA* __restrict__ A,
                const float* __restrict__ W,
                const float* __restrict__ bias,
                TC* __restrict__ C,
                float out_scale) {
  __shared__ alignas(16) __bf16 As[128][LDK];
  __shared__ alignas(16) __bf16 Ws[64][LDK];

  const int t = threadIdx.x;
  const int lane = t & 63;
  const int w = t >> 6;
  const int wr = w >> 1;
  const int wc = w & 1;
  const int col = lane & 15;
  const int quad = lane >> 4;
  const int m_blk = blockIdx.y * 128;
  const int n_blk = blockIdx.x * 64;

  f32x4 acc[4][2] = {};

  for (int k0 = 0; k0 < DMODEL; k0 += BK) {
    __syncthreads();
    if constexpr (std::is_same<TA, float>::value) {
      #pragma unroll
      for (int p = 0; p < 8; ++p) {
        const int r = p * 16 + (t >> 4);
        const int c = (t & 15) * 4;
        const float4 v =
            *(const float4*)(A + (size_t)(m_blk + r) * DMODEL + k0 + c);
        bf16x4 b = {(__bf16)v.x, (__bf16)v.y, (__bf16)v.z, (__bf16)v.w};
        *(bf16x4*)&As[r][c] = b;
      }
    } else {
      #pragma unroll
      for (int p = 0; p < 4; ++p) {
        const int r = p * 32 + (t >> 3);
        const int c = (t & 7) * 8;
        *(bf16x8*)&As[r][c] =
            *(const bf16x8*)((const __bf16*)A + (size_t)(m_blk + r) * DMODEL + k0 + c);
      }
    }
    #pragma unroll
    for (int p = 0; p < 4; ++p) {
      const int r = p * 16 + (t >> 4);
      const int c = (t & 15) * 4;
      const float4 v =
          *(const float4*)(W + (size_t)(n_blk + r) * DMODEL + k0 + c);
      bf16x4 b = {(__bf16)v.x, (__bf16)v.y, (__bf16)v.z, (__bf16)v.w};
      *(bf16x4*)&Ws[r][c] = b;
    }
    __syncthreads();

    #pragma unroll
    for (int kh = 0; kh < BK; kh += 32) {
      bf16x8 af[4], bfr[2];
      #pragma unroll
      for (int at = 0; at < 4; ++at)
        af[at] = *(const bf16x8*)&As[wr * 64 + at * 16 + col][kh + quad * 8];
      #pragma unroll
      for (int bt = 0; bt < 2; ++bt)
        bfr[bt] = *(const bf16x8*)&Ws[wc * 32 + bt * 16 + col][kh + quad * 8];
      #pragma unroll
      for (int at = 0; at < 4; ++at)
        #pragma unroll
        for (int bt = 0; bt < 2; ++bt)
          acc[at][bt] = __builtin_amdgcn_mfma_f32_16x16x32_bf16(
              af[at], bfr[bt], acc[at][bt], 0, 0, 0);
    }
  }

  #pragma unroll
  for (int at = 0; at < 4; ++at) {
    #pragma unroll
    for (int bt = 0; bt < 2; ++bt) {
      const int n = n_blk + wc * 32 + bt * 16 + col;
      const float b = bias[n];
      #pragma unroll
      for (int i = 0; i < 4; ++i) {
        const int m = m_blk + wr * 64 + at * 16 + quad * 4 + i;
        const float v = (acc[at][bt][i] + b) * out_scale;
        if constexpr (TRANS_C) store_c(&C[(size_t)n * SEQ + m], v);
        else                   store_c(&C[(size_t)m * DMODEL + n], v);
      }
    }
  }
}

// ---------------------------------------------------------------------------
// Flash attention = R19 body (verified 86.2 us), single dispatch.
// ---------------------------------------------------------------------------
__global__ __launch_bounds__(256, 4)
void flash_attn_splitN(const __hip_bfloat16* __restrict__ Q,
                       const __hip_bfloat16* __restrict__ K,
                       const __hip_bfloat16* __restrict__ Vt,
                       __hip_bfloat16* __restrict__ Op0,
                       __hip_bfloat16* __restrict__ Op1,
                       __hip_bfloat16* __restrict__ Op2,
                       __hip_bfloat16* __restrict__ Op3,
                       float* __restrict__ lsum_g) {
  __shared__ alignas(16) __hip_bfloat16 kt[64 * 64];   // [key][d]  8 KB
  __shared__ alignas(16) __hip_bfloat16 vtt[64 * 64];  // [d][key]  8 KB

  const int t = threadIdx.x;
  const int lane = t & 63;
  const int w = t >> 6;
  const int head = blockIdx.y;
  const int q0 = blockIdx.x * 128;
  const int z = blockIdx.z;
  const int nz = gridDim.z;
  const int l31 = lane & 31;
  const int hl = lane >> 5;

  __hip_bfloat16* O = (z == 0) ? Op0 : (z == 1) ? Op1 : (z == 2) ? Op2 : Op3;

  bf16x8 qf[4];
  {
    const __hip_bfloat16* qp =
        Q + (size_t)(q0 + w * 32 + l31) * DMODEL + head * DKH + hl * 8;
    #pragma unroll
    for (int db = 0; db < 4; ++db) qf[db] = *(const bf16x8*)(qp + db * 16);
  }

  f32x16 acc_o[2] = {};
  float lsa = 0.f, lsb = 0.f;

  const int sr = t >> 2;
  const int sc = (t & 3) * 16;
  const int seg = SEQ / nz;
  const int NT = seg / 64;
  const int kbeg = z * seg;

  const __hip_bfloat16* kgp = K + (size_t)(kbeg + sr) * DMODEL + head * DKH + sc;
  const __hip_bfloat16* vgp = Vt + (size_t)(head * DKH + sr) * SEQ + kbeg + sc;

  bf16x8 kr0 = *(const bf16x8*)kgp;
  bf16x8 kr1 = *(const bf16x8*)(kgp + 8);
  bf16x8 vr0 = *(const bf16x8*)vgp;
  bf16x8 vr1 = *(const bf16x8*)(vgp + 8);

  for (int ti = 0; ti < NT; ++ti) {
    __syncthreads();
    st8(kt, sr, sc, kr0);  st8(kt, sr, sc + 8, kr1);
    st8(vtt, sr, sc, vr0); st8(vtt, sr, sc + 8, vr1);
    __syncthreads();

    if (ti + 1 < NT) {
      const __hip_bfloat16* kn = kgp + (size_t)(ti + 1) * 64 * DMODEL;
      const __hip_bfloat16* vn = vgp + (ti + 1) * 64;
      kr0 = *(const bf16x8*)kn; kr1 = *(const bf16x8*)(kn + 8);
      vr0 = *(const bf16x8*)vn; vr1 = *(const bf16x8*)(vn + 8);
    }

    bf16x8 pa[4];
    #pragma unroll
    for (int kb = 0; kb < 2; ++kb) {
      f32x16 s = {};
      __builtin_amdgcn_s_setprio(1);
      #pragma unroll
      for (int db = 0; db < 4; ++db) {
        const bf16x8 kf = ld8(kt, kb * 32 + l31, db * 16 + hl * 8);
        s = __builtin_amdgcn_mfma_f32_32x32x16_bf16(kf, qf[db], s, 0, 0, 0);
      }
      __builtin_amdgcn_s_setprio(0);
      unsigned wp[8];
      #pragma unroll
      for (int i = 0; i < 8; ++i) {
        const float p0 = __builtin_amdgcn_exp2f(s[2 * i]);
        const float p1 = __builtin_amdgcn_exp2f(s[2 * i + 1]);
        lsa += p0; lsb += p1;
        wp[i] = pack2(p0, p1);
      }
      #pragma unroll
      for (int b = 0; b < 2; ++b) {
        unsigned a0 = wp[4 * b + 0], a2 = wp[4 * b + 2];
        unsigned a1 = wp[4 * b + 1], a3 = wp[4 * b + 3];
        asm("v_permlane32_swap_b32 %0, %1" : "+v"(a0), "+v"(a2));
        asm("v_permlane32_swap_b32 %0, %1" : "+v"(a1), "+v"(a3));
        W8 u;
        u.u[0] = a0; u.u[1] = a1; u.u[2] = a2; u.u[3] = a3;
        pa[kb * 2 + b] = u.v;
      }
    }

    __builtin_amdgcn_s_setprio(1);
    #pragma unroll
    for (int kq = 0; kq < 4; ++kq)
      #pragma unroll
      for (int db = 0; db < 2; ++db) {
        const bf16x8 vb = ld8(vtt, db * 32 + l31, kq * 16 + hl * 8);
        acc_o[db] = __builtin_amdgcn_mfma_f32_32x32x16_bf16(
            pa[kq], vb, acc_o[db], 0, 0, 0);
      }
    __builtin_amdgcn_s_setprio(0);
  }

  float lsumq = lsa + lsb;
  lsumq += __shfl_xor(lsumq, 32);
  if (lane < 32)
    lsum_g[((size_t)z * NH + head) * SEQ + q0 + w * 32 + lane] = lsumq;

  #pragma unroll
  for (int db = 0; db < 2; ++db) {
    #pragma unroll
    for (int r = 0; r < 16; ++r) {
      const int qr = q0 + w * 32 + (r & 3) + 8 * (r >> 2) + 4 * hl;
      const int cidx = head * DKH + db * 32 + l31;
      O[(size_t)qr * DMODEL + cidx] = __float2bfloat16(acc_o[db][r]);
    }
  }
}

// Combine: Ao = (sum_z Oz) / (sum_z lz).
__global__ __launch_bounds__(256)
void attn_combine(const __hip_bfloat16* __restrict__ Op0,
                  const __hip_bfloat16* __restrict__ Op1,
                  const __hip_bfloat16* __restrict__ Op2,
                  const __hip_bfloat16* __restrict__ Op3,
                  const float* __restrict__ ls,
                  __hip_bfloat16* __restrict__ Ao, int nz) {
  const size_t i = ((size_t)blockIdx.x * 256 + threadIdx.x) * 8;
  const int qrow = (int)(i >> 10);
  const int h = (int)((i & 1023) >> 6);
  float lsum = ls[(size_t)h * SEQ + qrow] +
               ls[(size_t)(NH + h) * SEQ + qrow];
  const bf16x8 a = *(const bf16x8*)(Op0 + i);
  const bf16x8 b = *(const bf16x8*)(Op1 + i);
  float s[8];
  #pragma unroll
  for (int j = 0; j < 8; ++j) s[j] = (float)a[j] + (float)b[j];
  if (nz == 4) {
    lsum += ls[(size_t)(2 * NH + h) * SEQ + qrow] +
            ls[(size_t)(3 * NH + h) * SEQ + qrow];
    const bf16x8 c = *(const bf16x8*)(Op2 + i);
    const bf16x8 d = *(const bf16x8*)(Op3 + i);
    #pragma unroll
    for (int j = 0; j < 8; ++j) s[j] += (float)c[j] + (float)d[j];
  }
  const float inv = 1.f / lsum;
  bf16x8 r;
  #pragma unroll
  for (int j = 0; j < 8; ++j) r[j] = (__bf16)(s[j] * inv);
  *(bf16x8*)(Ao + i) = r;
}

// ---------------------------------------------------------------------------
// FALLBACK flash (R12 mono version) — used only if ws_size < 40 MB.
// ---------------------------------------------------------------------------
constexpr int LDP = 72;
constexpr float SHIFT = 8.0f;

__global__ __launch_bounds__(256)
void flash_attn_mono(const __hip_bfloat16* __restrict__ Q,
                     const __hip_bfloat16* __restrict__ K,
                     const __hip_bfloat16* __restrict__ Vt,
                     __hip_bfloat16* __restrict__ O) {
  __shared__ alignas(16) __hip_bfloat16 kt[64][LDP];
  __shared__ alignas(16) __hip_bfloat16 vtt[DKH][LDP];
  __shared__ alignas(16) __hip_bfloat16 plT[4][32][LDP];

  const int t = threadIdx.x;
  const int lane = t & 63;
  const int w = t >> 6;
  const int h = blockIdx.y;
  const int q0 = blockIdx.x * 128;
  const int col = lane & 15;
  const int quad = lane >> 4;

  bf16x8 qf[2][2];
  #pragma unroll
  for (int rg = 0; rg < 2; ++rg) {
    const __hip_bfloat16* qptr =
        Q + (size_t)(q0 + w * 32 + rg * 16 + col) * DMODEL + h * DKH + quad * 8;
    qf[rg][0] = *(const bf16x8*)qptr;
    qf[rg][1] = *(const bf16x8*)(qptr + 32);
  }

  f32x4 acc_o[2][4] = {};
  float lsumq[2] = {0.f, 0.f};
  const int sr = t >> 2;
  const int sc = (t & 3) * 16;

  for (int k0 = 0; k0 < SEQ; k0 += 64) {
    __syncthreads();
    const __hip_bfloat16* kg = K + (size_t)(k0 + sr) * DMODEL + h * DKH + sc;
    *(bf16x8*)&kt[sr][sc]     = *(const bf16x8*)kg;
    *(bf16x8*)&kt[sr][sc + 8] = *(const bf16x8*)(kg + 8);
    const __hip_bfloat16* vg = Vt + (size_t)(h * DKH + sr) * SEQ + k0 + sc;
    *(bf16x8*)&vtt[sr][sc]     = *(const bf16x8*)vg;
    *(bf16x8*)&vtt[sr][sc + 8] = *(const bf16x8*)(vg + 8);
    __syncthreads();

    #pragma unroll
    for (int jt = 0; jt < 4; ++jt) {
      const bf16x8 kf0 = *(const bf16x8*)&kt[jt * 16 + col][quad * 8];
      const bf16x8 kf1 = *(const bf16x8*)&kt[jt * 16 + col][quad * 8 + 32];
      #pragma unroll
      for (int rg = 0; rg < 2; ++rg) {
        f32x4 zz = {0.f, 0.f, 0.f, 0.f};
        zz = __builtin_amdgcn_mfma_f32_16x16x32_bf16(kf0, qf[rg][0], zz, 0, 0, 0);
        zz = __builtin_amdgcn_mfma_f32_16x16x32_bf16(kf1, qf[rg][1], zz, 0, 0, 0);
        bf16x4 pk;
        #pragma unroll
        for (int r = 0; r < 4; ++r) {
          const float p = __expf(zz[r] - SHIFT);
          lsumq[rg] += p;
          pk[r] = (__bf16)p;
        }
        *(bf16x4*)&plT[w][rg * 16 + col][jt * 16 + quad * 4] = pk;
      }
    }

    bf16x8 pa[2][2];
    #pragma unroll
    for (int rg = 0; rg < 2; ++rg) {
      pa[rg][0] = *(const bf16x8*)&plT[w][rg * 16 + col][quad * 8];
      pa[rg][1] = *(const bf16x8*)&plT[w][rg * 16 + col][quad * 8 + 32];
    }
    #pragma unroll
    for (int jt = 0; jt < 4; ++jt) {
      const bf16x8 vb0 = *(const bf16x8*)&vtt[jt * 16 + col][quad * 8];
      const bf16x8 vb1 = *(const bf16x8*)&vtt[jt * 16 + col][quad * 8 + 32];
      #pragma unroll
      for (int rg = 0; rg < 2; ++rg) {
        acc_o[rg][jt] = __builtin_amdgcn_mfma_f32_16x16x32_bf16(
            pa[rg][0], vb0, acc_o[rg][jt], 0, 0, 0);
        acc_o[rg][jt] = __builtin_amdgcn_mfma_f32_16x16x32_bf16(
            pa[rg][1], vb1, acc_o[rg][jt], 0, 0, 0);
      }
    }
  }

  #pragma unroll
  for (int rg = 0; rg < 2; ++rg) {
    lsumq[rg] += __shfl_xor(lsumq[rg], 16);
    lsumq[rg] += __shfl_xor(lsumq[rg], 32);
  }
  float invr[2][4];
  #pragma unroll
  for (int rg = 0; rg < 2; ++rg)
    #pragma unroll
    for (int r = 0; r < 4; ++r)
      invr[rg][r] = 1.f / __shfl(lsumq[rg], quad * 4 + r);

  #pragma unroll
  for (int rg = 0; rg < 2; ++rg) {
    #pragma unroll
    for (int jt = 0; jt < 4; ++jt) {
      #pragma unroll
      for (int r = 0; r < 4; ++r) {
        const int qr = q0 + w * 32 + rg * 16 + quad * 4 + r;
        const int c = h * DKH + jt * 16 + col;
        O[(size_t)qr * DMODEL + c] = __float2bfloat16(acc_o[rg][jt][r] * invr[rg][r]);
      }
    }
  }
}

// ---------------------------------------------------------------------------
// Interface: inputs fp32 dict-order, output fp32.
// FAST path (ws_size >= 40 MB), 6 dispatches, no memcpy.
//   d_out: Qp [0,8M) | Xq [8,16M) -> Opart2 (z4)   (dead before final write)
//   ws: Kp[0,8) Vt[8,16) | Xk[16,24)->Opart0->Ao | Xv[24,32)->Opart1 |
//       Wqb[32,34)->lsum@33M | Wkb[34,36) Wvb[36,38) Wob[38,40) |
//       [40,48) -> Opart3 (only if ws >= 48 MB; else nz=2)
// ---------------------------------------------------------------------------
extern "C" void kernel_launch(void* const* d_in, const int* in_sizes, int n_in,
                              void* d_out, int out_size, void* d_ws, size_t ws_size,
                              hipStream_t stream) {
  const float* query = (const float*)d_in[0];
  const float* key   = (const float*)d_in[1];
  const float* value = (const float*)d_in[2];
  const float* W_q   = (const float*)d_in[3];
  const float* b_q   = (const float*)d_in[4];
  const float* W_k   = (const float*)d_in[5];
  const float* b_k   = (const float*)d_in[6];
  const float* W_v   = (const float*)d_in[7];
  const float* b_v   = (const float*)d_in[8];
  const float* W_o   = (const float*)d_in[9];
  const float* b_o   = (const float*)d_in[10];

  float* out = (float*)d_out;
  const size_t mat = (size_t)SEQ * DMODEL;
  const size_t MB = 1024 * 1024;

  char* ws = (char*)d_ws;
  __hip_bfloat16* Qp = (__hip_bfloat16*)d_out;            // d_out [0,8M)
  __hip_bfloat16* Kp = (__hip_bfloat16*)ws;               // ws [0,8M)
  __hip_bfloat16* Vt = Kp + mat;                          // ws [8,16M)

  dim3 gblock(256);

  if (ws_size >= 40 * MB) {
    __bf16* Xq  = (__bf16*)((char*)d_out + 8 * MB);
    __bf16* Xk  = (__bf16*)(ws + 16 * MB);
    __bf16* Xv  = (__bf16*)(ws + 24 * MB);
    __bf16* Wqb = (__bf16*)(ws + 32 * MB);
    __bf16* Wkb = (__bf16*)(ws + 34 * MB);
    __bf16* Wvb = (__bf16*)(ws + 36 * MB);
    __bf16* Wob = (__bf16*)(ws + 38 * MB);
    __hip_bfloat16* Op0 = (__hip_bfloat16*)(ws + 16 * MB);
    __hip_bfloat16* Op1 = (__hip_bfloat16*)(ws + 24 * MB);
    __hip_bfloat16* Op2 = (__hip_bfloat16*)((char*)d_out + 8 * MB);  // Xq dead
    __hip_bfloat16* Op3 = (__hip_bfloat16*)(ws + 40 * MB);
    float* lsum = (float*)(ws + 33 * MB);   // up to 1 MB (nz=4); Wqb dead
    __hip_bfloat16* Ao = (__hip_bfloat16*)(ws + 16 * MB);  // combine in place

    const int nz = (ws_size >= 48 * MB) ? 4 : 2;

    hipLaunchKernelGGL(cvt_all, dim3(8192), gblock, 0, stream,
                       query, key, value, W_q, W_k, W_v, W_o,
                       Xq, Xk, Xv, Wqb, Wkb, Wvb, Wob);

    // QKV via 8-phase 256^2 template: (4, 16, 3) = 192 blocks x 512 thr.
    dim3 qkvgrid(DMODEL / 256, SEQ / 256, 3);
    hipLaunchKernelGGL(gemm_qkv8, qkvgrid, dim3(512), 0, stream,
                       Xq, Xk, Xv, Wqb, Wkb, Wvb, b_q, b_k, b_v,
                       Qp, Kp, Vt);

    dim3 agrid(SEQ / 128, NH, nz);  // single flash dispatch (R19 config)
    hipLaunchKernelGGL(flash_attn_splitN, agrid, gblock, 0, stream,
                       Qp, Kp, Vt, Op0, Op1, Op2, Op3, lsum);
    hipLaunchKernelGGL(attn_combine, dim3(2048), gblock, 0, stream,
                       Op0, Op1, Op2, Op3, lsum, Ao, nz);

    dim3 ogrid(DMODEL / 64, SEQ / 128);  // (16, 32) = 512 blocks
    hipLaunchKernelGGL((gemm128<float, false>), ogrid, gblock, 0, stream,
                       (const __bf16*)Ao, Wob, b_o, out, 1.0f);
  } else {
    // fallback: R10-proven plan (16 MB ws)
    __hip_bfloat16* Ao = Qp + mat;         // d_out [8,16M)
    float* Cw = (float*)d_ws;
    dim3 fgrid(DMODEL / 64, SEQ / 128);    // (16, 32) for gemm_tiled
    hipLaunchKernelGGL((gemm_tiled<float, __hip_bfloat16, false>), fgrid, gblock,
                       0, stream, query, W_q, b_q, Qp, SCALE);
    hipLaunchKernelGGL((gemm_tiled<float, __hip_bfloat16, false>), fgrid, gblock,
                       0, stream, key, W_k, b_k, Kp, 1.0f);
    hipLaunchKernelGGL((gemm_tiled<float, __hip_bfloat16, true>), fgrid, gblock,
                       0, stream, value, W_v, b_v, Vt, 1.0f);
    dim3 agrid(SEQ / 128, NH);
    hipLaunchKernelGGL(flash_attn_mono, agrid, gblock, 0, stream, Qp, Kp, Vt, Ao);
    hipLaunchKernelGGL((gemm_tiled<__hip_bfloat16, float, false>), fgrid, gblock,
                       0, stream, Ao, W_o, b_o, Cw, 1.0f);
    hipMemcpyAsync(out, Cw, mat * sizeof(float), hipMemcpyDeviceToDevice, stream);
  }
}

// Round 12
// 264.105 us; speedup vs baseline: 1.2121x; 1.2121x over previous
//
#include <hip/hip_runtime.h>
#include <hip/hip_bf16.h>
#include <type_traits>

// Problem constants
constexpr int SEQ = 4096;
constexpr int DMODEL = 1024;
constexpr int NH = 16;
constexpr int DKH = 64;          // head dim
constexpr float SCALE = 0.125f;  // 1/sqrt(64)
// fold log2(e) into Q scale so softmax uses raw v_exp_f32 (2^x).
constexpr float SCALE2 = 0.125f * 1.4426950408889634f;

typedef __bf16 bf16x8 __attribute__((ext_vector_type(8)));
typedef __bf16 bf16x4 __attribute__((ext_vector_type(4)));
typedef float f32x4 __attribute__((ext_vector_type(4)));
typedef float f32x16 __attribute__((ext_vector_type(16)));
typedef unsigned int u32x4 __attribute__((ext_vector_type(4)));
union W8 { u32x4 u; bf16x8 v; };

__device__ inline void store_c(__hip_bfloat16* p, float v) { *p = __float2bfloat16(v); }
__device__ inline void store_c(float* p, float v) { *p = v; }

typedef const void __attribute__((address_space(1)))* gas_ptr;
typedef void __attribute__((address_space(3)))* las_ptr;
__device__ inline void load_lds_16B(const void* g, void* l) {
  __builtin_amdgcn_global_load_lds((gas_ptr)g, (las_ptr)l, 16, 0, 0);
}

// pack two f32 -> one u32 holding 2 bf16 (compiler emits cvt_pk).
__device__ inline unsigned pack2(float a, float b) {
  union { __bf16 h[2]; unsigned u; } p;
  p.h[0] = (__bf16)a; p.h[1] = (__bf16)b;
  return p.u;
}

// XOR-swizzled [64][64] bf16 LDS tile accessors (16B granularity, T2 pattern).
__device__ inline void st8(__hip_bfloat16* buf, int row, int col, bf16x8 v) {
  *(bf16x8*)(buf + row * 64 + (col ^ ((row & 7) << 3))) = v;
}
__device__ inline bf16x8 ld8(const __hip_bfloat16* buf, int row, int col) {
  return *(const bf16x8*)(buf + row * 64 + (col ^ ((row & 7) << 3)));
}

// ---------------------------------------------------------------------------
// Fused fp32 -> bf16 conversion for all 7 tensors (1 launch instead of 7).
// ---------------------------------------------------------------------------
__global__ __launch_bounds__(256)
void cvt_all(const float* __restrict__ q, const float* __restrict__ k,
             const float* __restrict__ v, const float* __restrict__ wq,
             const float* __restrict__ wk, const float* __restrict__ wv,
             const float* __restrict__ wo,
             __bf16* __restrict__ Xq, __bf16* __restrict__ Xk,
             __bf16* __restrict__ Xv, __bf16* __restrict__ Wqb,
             __bf16* __restrict__ Wkb, __bf16* __restrict__ Wvb,
             __bf16* __restrict__ Wob) {
  const int b = blockIdx.x;
  const float* src; __bf16* dst; size_t base;
  if      (b < 2048) { src = q;  dst = Xq;  base = b; }
  else if (b < 4096) { src = k;  dst = Xk;  base = b - 2048; }
  else if (b < 6144) { src = v;  dst = Xv;  base = b - 4096; }
  else if (b < 6656) { src = wq; dst = Wqb; base = b - 6144; }
  else if (b < 7168) { src = wk; dst = Wkb; base = b - 6656; }
  else if (b < 7680) { src = wv; dst = Wvb; base = b - 7168; }
  else               { src = wo; dst = Wob; base = b - 7680; }
  const size_t i = (base * 256 + threadIdx.x) * 8;
  const float4 a = *(const float4*)(src + i);
  const float4 c = *(const float4*)(src + i + 4);
  bf16x8 r = {(__bf16)a.x, (__bf16)a.y, (__bf16)a.z, (__bf16)a.w,
              (__bf16)c.x, (__bf16)c.y, (__bf16)c.z, (__bf16)c.w};
  *(bf16x8*)(dst + i) = r;
}

// ---------------------------------------------------------------------------
// R25: both GEMMs keep the verified 2-barrier m97 structure but kill the
// 16-way frag-read bank conflicts (measured: 1.42e7 cy = ~40% of qkv time).
// Involution S(row, blk) = blk ^ (row&7) at 16B granularity (rule #21):
//  * stage: linear global_load_lds DEST + inverse-swizzled global SOURCE
//    column ((sc8 ^ (srow&7))*8) — wave still touches the same 128B lines.
//  * frag read: col offset (kh + quad*8) ^ ((col&7)*8); row&7 == col&7 since
//    all row terms except col are multiples of 8.
// Read spread: 16 lanes/4-bank-group -> 8/group (b128 bandwidth-optimal).
// ---------------------------------------------------------------------------
constexpr int BK = 64;

template <typename TC, bool TRANS_C>
__global__ __launch_bounds__(256)
void gemm128(const __bf16* __restrict__ A,
             const __bf16* __restrict__ W,
             const float* __restrict__ bias,
             TC* __restrict__ C,
             float out_scale) {
  __shared__ alignas(16) __bf16 As[128][64];  // 16 KB
  __shared__ alignas(16) __bf16 Ws[64][64];   // 8 KB

  const int t = threadIdx.x;
  const int lane = t & 63;
  const int w = t >> 6;
  const int wr = w >> 1;
  const int wc = w & 1;
  const int col = lane & 15;
  const int quad = lane >> 4;

  // XCD-clustered block decode (grid (16,32) = 512 blocks)
  const int L = blockIdx.x + 16 * blockIdx.y;
  const int xcd = L & 7;
  const int c = L >> 3;
  const int m_blk = (xcd * 4 + (c >> 4)) * 128;
  const int n_blk = (c & 15) * 64;

  const int srow = t >> 3;                       // 0..31
  const int scol_l = (t & 7) * 8;                // linear LDS col this lane fills
  const int scol_g = ((t & 7) ^ (srow & 7)) * 8; // pre-swizzled global col
  const int rsw = (col & 7) * 8;                 // read-side swizzle

  f32x4 acc[4][2] = {};

  for (int k0 = 0; k0 < DMODEL; k0 += BK) {
    __syncthreads();
    #pragma unroll
    for (int p = 0; p < 4; ++p)
      load_lds_16B(A + (size_t)(m_blk + p * 32 + srow) * DMODEL + k0 + scol_g,
                   &As[p * 32 + srow][scol_l]);
    #pragma unroll
    for (int p = 0; p < 2; ++p)
      load_lds_16B(W + (size_t)(n_blk + p * 32 + srow) * DMODEL + k0 + scol_g,
                   &Ws[p * 32 + srow][scol_l]);
    __syncthreads();

    #pragma unroll
    for (int kh = 0; kh < BK; kh += 32) {
      bf16x8 af[4], bfr[2];
      #pragma unroll
      for (int at = 0; at < 4; ++at)
        af[at] = *(const bf16x8*)&As[wr * 64 + at * 16 + col][(kh + quad * 8) ^ rsw];
      #pragma unroll
      for (int bt = 0; bt < 2; ++bt)
        bfr[bt] = *(const bf16x8*)&Ws[wc * 32 + bt * 16 + col][(kh + quad * 8) ^ rsw];
      #pragma unroll
      for (int at = 0; at < 4; ++at)
        #pragma unroll
        for (int bt = 0; bt < 2; ++bt)
          acc[at][bt] = __builtin_amdgcn_mfma_f32_16x16x32_bf16(
              af[at], bfr[bt], acc[at][bt], 0, 0, 0);
    }
  }

  #pragma unroll
  for (int at = 0; at < 4; ++at) {
    #pragma unroll
    for (int bt = 0; bt < 2; ++bt) {
      const int n = n_blk + wc * 32 + bt * 16 + col;
      const float b = bias[n];
      #pragma unroll
      for (int i = 0; i < 4; ++i) {
        const int m = m_blk + wr * 64 + at * 16 + quad * 4 + i;
        const float v = (acc[at][bt][i] + b) * out_scale;
        if constexpr (TRANS_C) store_c(&C[(size_t)n * SEQ + m], v);
        else                   store_c(&C[(size_t)m * DMODEL + n], v);
      }
    }
  }
}

// ---------------------------------------------------------------------------
// Fused Q/K/V projection GEMM: R17 tile config (BM=128, BN=64, verified
// 58.7 us) + XCD decode + R25 conflict-fix swizzle. Grid MUST be (16,32,3).
// z==2 (V) writes transposed (Vt [DMODEL][SEQ]); z==0 carries SCALE2.
// R24 lesson: 8-phase port at 1 block/CU was 1.5x SLOWER (conflicted frag
// reads became the unhidden critical path). Fix the conflicts instead.
// ---------------------------------------------------------------------------
__global__ __launch_bounds__(256)
void gemm_qkv(const __bf16* __restrict__ Xq, const __bf16* __restrict__ Xk,
              const __bf16* __restrict__ Xv, const __bf16* __restrict__ Wq,
              const __bf16* __restrict__ Wk, const __bf16* __restrict__ Wv,
              const float* __restrict__ bq, const float* __restrict__ bk,
              const float* __restrict__ bv,
              __hip_bfloat16* __restrict__ Cq, __hip_bfloat16* __restrict__ Ck,
              __hip_bfloat16* __restrict__ Cv) {
  __shared__ alignas(16) __bf16 As[128][64];  // 16 KB
  __shared__ alignas(16) __bf16 Ws[64][64];   // 8 KB

  // XCD-clustered block decode (grid (16,32,3) = 1536 blocks)
  const int L = blockIdx.x + 16 * (blockIdx.y + 32 * blockIdx.z);
  const int xcd = L & 7;
  const int cc = L >> 3;
  const int z = cc / 64;
  const int c2 = cc & 63;
  const int m_blk = (xcd * 4 + (c2 >> 4)) * 128;
  const int n_blk = (c2 & 15) * 64;

  const __bf16* A = (z == 0) ? Xq : (z == 1) ? Xk : Xv;
  const __bf16* W = (z == 0) ? Wq : (z == 1) ? Wk : Wv;
  const float* bias = (z == 0) ? bq : (z == 1) ? bk : bv;
  __hip_bfloat16* C = (z == 0) ? Cq : (z == 1) ? Ck : Cv;
  const float out_scale = (z == 0) ? SCALE2 : 1.0f;

  const int t = threadIdx.x;
  const int lane = t & 63;
  const int w = t >> 6;
  const int wr = w >> 1;
  const int wc = w & 1;
  const int col = lane & 15;
  const int quad = lane >> 4;

  const int srow = t >> 3;
  const int scol_l = (t & 7) * 8;
  const int scol_g = ((t & 7) ^ (srow & 7)) * 8;
  const int rsw = (col & 7) * 8;

  f32x4 acc[4][2] = {};

  for (int k0 = 0; k0 < DMODEL; k0 += BK) {
    __syncthreads();
    #pragma unroll
    for (int p = 0; p < 4; ++p)
      load_lds_16B(A + (size_t)(m_blk + p * 32 + srow) * DMODEL + k0 + scol_g,
                   &As[p * 32 + srow][scol_l]);
    #pragma unroll
    for (int p = 0; p < 2; ++p)
      load_lds_16B(W + (size_t)(n_blk + p * 32 + srow) * DMODEL + k0 + scol_g,
                   &Ws[p * 32 + srow][scol_l]);
    __syncthreads();

    #pragma unroll
    for (int kh = 0; kh < BK; kh += 32) {
      bf16x8 af[4], bfr[2];
      #pragma unroll
      for (int at = 0; at < 4; ++at)
        af[at] = *(const bf16x8*)&As[wr * 64 + at * 16 + col][(kh + quad * 8) ^ rsw];
      #pragma unroll
      for (int bt = 0; bt < 2; ++bt)
        bfr[bt] = *(const bf16x8*)&Ws[wc * 32 + bt * 16 + col][(kh + quad * 8) ^ rsw];
      #pragma unroll
      for (int at = 0; at < 4; ++at)
        #pragma unroll
        for (int bt = 0; bt < 2; ++bt)
          acc[at][bt] = __builtin_amdgcn_mfma_f32_16x16x32_bf16(
              af[at], bfr[bt], acc[at][bt], 0, 0, 0);
    }
  }

  #pragma unroll
  for (int at = 0; at < 4; ++at) {
    #pragma unroll
    for (int bt = 0; bt < 2; ++bt) {
      const int n = n_blk + wc * 32 + bt * 16 + col;
      const float b = bias[n];
      #pragma unroll
      for (int i = 0; i < 4; ++i) {
        const int m = m_blk + wr * 64 + at * 16 + quad * 4 + i;
        const float v = (acc[at][bt][i] + b) * out_scale;
        if (z == 2) C[(size_t)n * SEQ + m] = __float2bfloat16(v);
        else        C[(size_t)m * DMODEL + n] = __float2bfloat16(v);
      }
    }
  }
}

// ---------------------------------------------------------------------------
// FALLBACK GEMM — unchanged (only used if ws_size < 40 MB).
// ---------------------------------------------------------------------------
constexpr int LDK = 72;

template <typename TA, typename TC, bool TRANS_C>
__global__ __launch_bounds__(256)
void gemm_tiled(const TA* __restrict__ A,
                const float* __restrict__ W,
                const float* __restrict__ bias,
                TC* __restrict__ C,
                float out_scale) {
  __shared__ alignas(16) __bf16 As[128][LDK];
  __shared__ alignas(16) __bf16 Ws[64][LDK];

  const int t = threadIdx.x;
  const int lane = t & 63;
  const int w = t >> 6;
  const int wr = w >> 1;
  const int wc = w & 1;
  const int col = lane & 15;
  const int quad = lane >> 4;
  const int m_blk = blockIdx.y * 128;
  const int n_blk = blockIdx.x * 64;

  f32x4 acc[4][2] = {};

  for (int k0 = 0; k0 < DMODEL; k0 += BK) {
    __syncthreads();
    if constexpr (std::is_same<TA, float>::value) {
      #pragma unroll
      for (int p = 0; p < 8; ++p) {
        const int r = p * 16 + (t >> 4);
        const int c = (t & 15) * 4;
        const float4 v =
            *(const float4*)(A + (size_t)(m_blk + r) * DMODEL + k0 + c);
        bf16x4 b = {(__bf16)v.x, (__bf16)v.y, (__bf16)v.z, (__bf16)v.w};
        *(bf16x4*)&As[r][c] = b;
      }
    } else {
      #pragma unroll
      for (int p = 0; p < 4; ++p) {
        const int r = p * 32 + (t >> 3);
        const int c = (t & 7) * 8;
        *(bf16x8*)&As[r][c] =
            *(const bf16x8*)((const __bf16*)A + (size_t)(m_blk + r) * DMODEL + k0 + c);
      }
    }
    #pragma unroll
    for (int p = 0; p < 4; ++p) {
      const int r = p * 16 + (t >> 4);
      const int c = (t & 15) * 4;
      const float4 v =
          *(const float4*)(W + (size_t)(n_blk + r) * DMODEL + k0 + c);
      bf16x4 b = {(__bf16)v.x, (__bf16)v.y, (__bf16)v.z, (__bf16)v.w};
      *(bf16x4*)&Ws[r][c] = b;
    }
    __syncthreads();

    #pragma unroll
    for (int kh = 0; kh < BK; kh += 32) {
      bf16x8 af[4], bfr[2];
      #pragma unroll
      for (int at = 0; at < 4; ++at)
        af[at] = *(const bf16x8*)&As[wr * 64 + at * 16 + col][kh + quad * 8];
      #pragma unroll
      for (int bt = 0; bt < 2; ++bt)
        bfr[bt] = *(const bf16x8*)&Ws[wc * 32 + bt * 16 + col][kh + quad * 8];
      #pragma unroll
      for (int at = 0; at < 4; ++at)
        #pragma unroll
        for (int bt = 0; bt < 2; ++bt)
          acc[at][bt] = __builtin_amdgcn_mfma_f32_16x16x32_bf16(
              af[at], bfr[bt], acc[at][bt], 0, 0, 0);
    }
  }

  #pragma unroll
  for (int at = 0; at < 4; ++at) {
    #pragma unroll
    for (int bt = 0; bt < 2; ++bt) {
      const int n = n_blk + wc * 32 + bt * 16 + col;
      const float b = bias[n];
      #pragma unroll
      for (int i = 0; i < 4; ++i) {
        const int m = m_blk + wr * 64 + at * 16 + quad * 4 + i;
        const float v = (acc[at][bt][i] + b) * out_scale;
        if constexpr (TRANS_C) store_c(&C[(size_t)n * SEQ + m], v);
        else                   store_c(&C[(size_t)m * DMODEL + n], v);
      }
    }
  }
}

// ---------------------------------------------------------------------------
// Flash attention = R19 body (verified 86.2 us), single dispatch.
// ---------------------------------------------------------------------------
__global__ __launch_bounds__(256, 4)
void flash_attn_splitN(const __hip_bfloat16* __restrict__ Q,
                       const __hip_bfloat16* __restrict__ K,
                       const __hip_bfloat16* __restrict__ Vt,
                       __hip_bfloat16* __restrict__ Op0,
                       __hip_bfloat16* __restrict__ Op1,
                       __hip_bfloat16* __restrict__ Op2,
                       __hip_bfloat16* __restrict__ Op3,
                       float* __restrict__ lsum_g) {
  __shared__ alignas(16) __hip_bfloat16 kt[64 * 64];   // [key][d]  8 KB
  __shared__ alignas(16) __hip_bfloat16 vtt[64 * 64];  // [d][key]  8 KB

  const int t = threadIdx.x;
  const int lane = t & 63;
  const int w = t >> 6;
  const int head = blockIdx.y;
  const int q0 = blockIdx.x * 128;
  const int z = blockIdx.z;
  const int nz = gridDim.z;
  const int l31 = lane & 31;
  const int hl = lane >> 5;

  __hip_bfloat16* O = (z == 0) ? Op0 : (z == 1) ? Op1 : (z == 2) ? Op2 : Op3;

  bf16x8 qf[4];
  {
    const __hip_bfloat16* qp =
        Q + (size_t)(q0 + w * 32 + l31) * DMODEL + head * DKH + hl * 8;
    #pragma unroll
    for (int db = 0; db < 4; ++db) qf[db] = *(const bf16x8*)(qp + db * 16);
  }

  f32x16 acc_o[2] = {};
  float lsa = 0.f, lsb = 0.f;

  const int sr = t >> 2;
  const int sc = (t & 3) * 16;
  const int seg = SEQ / nz;
  const int NT = seg / 64;
  const int kbeg = z * seg;

  const __hip_bfloat16* kgp = K + (size_t)(kbeg + sr) * DMODEL + head * DKH + sc;
  const __hip_bfloat16* vgp = Vt + (size_t)(head * DKH + sr) * SEQ + kbeg + sc;

  bf16x8 kr0 = *(const bf16x8*)kgp;
  bf16x8 kr1 = *(const bf16x8*)(kgp + 8);
  bf16x8 vr0 = *(const bf16x8*)vgp;
  bf16x8 vr1 = *(const bf16x8*)(vgp + 8);

  for (int ti = 0; ti < NT; ++ti) {
    __syncthreads();
    st8(kt, sr, sc, kr0);  st8(kt, sr, sc + 8, kr1);
    st8(vtt, sr, sc, vr0); st8(vtt, sr, sc + 8, vr1);
    __syncthreads();

    if (ti + 1 < NT) {
      const __hip_bfloat16* kn = kgp + (size_t)(ti + 1) * 64 * DMODEL;
      const __hip_bfloat16* vn = vgp + (ti + 1) * 64;
      kr0 = *(const bf16x8*)kn; kr1 = *(const bf16x8*)(kn + 8);
      vr0 = *(const bf16x8*)vn; vr1 = *(const bf16x8*)(vn + 8);
    }

    bf16x8 pa[4];
    #pragma unroll
    for (int kb = 0; kb < 2; ++kb) {
      f32x16 s = {};
      __builtin_amdgcn_s_setprio(1);
      #pragma unroll
      for (int db = 0; db < 4; ++db) {
        const bf16x8 kf = ld8(kt, kb * 32 + l31, db * 16 + hl * 8);
        s = __builtin_amdgcn_mfma_f32_32x32x16_bf16(kf, qf[db], s, 0, 0, 0);
      }
      __builtin_amdgcn_s_setprio(0);
      unsigned wp[8];
      #pragma unroll
      for (int i = 0; i < 8; ++i) {
        const float p0 = __builtin_amdgcn_exp2f(s[2 * i]);
        const float p1 = __builtin_amdgcn_exp2f(s[2 * i + 1]);
        lsa += p0; lsb += p1;
        wp[i] = pack2(p0, p1);
      }
      #pragma unroll
      for (int b = 0; b < 2; ++b) {
        unsigned a0 = wp[4 * b + 0], a2 = wp[4 * b + 2];
        unsigned a1 = wp[4 * b + 1], a3 = wp[4 * b + 3];
        asm("v_permlane32_swap_b32 %0, %1" : "+v"(a0), "+v"(a2));
        asm("v_permlane32_swap_b32 %0, %1" : "+v"(a1), "+v"(a3));
        W8 u;
        u.u[0] = a0; u.u[1] = a1; u.u[2] = a2; u.u[3] = a3;
        pa[kb * 2 + b] = u.v;
      }
    }

    __builtin_amdgcn_s_setprio(1);
    #pragma unroll
    for (int kq = 0; kq < 4; ++kq)
      #pragma unroll
      for (int db = 0; db < 2; ++db) {
        const bf16x8 vb = ld8(vtt, db * 32 + l31, kq * 16 + hl * 8);
        acc_o[db] = __builtin_amdgcn_mfma_f32_32x32x16_bf16(
            pa[kq], vb, acc_o[db], 0, 0, 0);
      }
    __builtin_amdgcn_s_setprio(0);
  }

  float lsumq = lsa + lsb;
  lsumq += __shfl_xor(lsumq, 32);
  if (lane < 32)
    lsum_g[((size_t)z * NH + head) * SEQ + q0 + w * 32 + lane] = lsumq;

  #pragma unroll
  for (int db = 0; db < 2; ++db) {
    #pragma unroll
    for (int r = 0; r < 16; ++r) {
      const int qr = q0 + w * 32 + (r & 3) + 8 * (r >> 2) + 4 * hl;
      const int cidx = head * DKH + db * 32 + l31;
      O[(size_t)qr * DMODEL + cidx] = __float2bfloat16(acc_o[db][r]);
    }
  }
}

// Combine: Ao = (sum_z Oz) / (sum_z lz).
__global__ __launch_bounds__(256)
void attn_combine(const __hip_bfloat16* __restrict__ Op0,
                  const __hip_bfloat16* __restrict__ Op1,
                  const __hip_bfloat16* __restrict__ Op2,
                  const __hip_bfloat16* __restrict__ Op3,
                  const float* __restrict__ ls,
                  __hip_bfloat16* __restrict__ Ao, int nz) {
  const size_t i = ((size_t)blockIdx.x * 256 + threadIdx.x) * 8;
  const int qrow = (int)(i >> 10);
  const int h = (int)((i & 1023) >> 6);
  float lsum = ls[(size_t)h * SEQ + qrow] +
               ls[(size_t)(NH + h) * SEQ + qrow];
  const bf16x8 a = *(const bf16x8*)(Op0 + i);
  const bf16x8 b = *(const bf16x8*)(Op1 + i);
  float s[8];
  #pragma unroll
  for (int j = 0; j < 8; ++j) s[j] = (float)a[j] + (float)b[j];
  if (nz == 4) {
    lsum += ls[(size_t)(2 * NH + h) * SEQ + qrow] +
            ls[(size_t)(3 * NH + h) * SEQ + qrow];
    const bf16x8 c = *(const bf16x8*)(Op2 + i);
    const bf16x8 d = *(const bf16x8*)(Op3 + i);
    #pragma unroll
    for (int j = 0; j < 8; ++j) s[j] += (float)c[j] + (float)d[j];
  }
  const float inv = 1.f / lsum;
  bf16x8 r;
  #pragma unroll
  for (int j = 0; j < 8; ++j) r[j] = (__bf16)(s[j] * inv);
  *(bf16x8*)(Ao + i) = r;
}

// ---------------------------------------------------------------------------
// FALLBACK flash (R12 mono version) — used only if ws_size < 40 MB.
// ---------------------------------------------------------------------------
constexpr int LDP = 72;
constexpr float SHIFT = 8.0f;

__global__ __launch_bounds__(256)
void flash_attn_mono(const __hip_bfloat16* __restrict__ Q,
                     const __hip_bfloat16* __restrict__ K,
                     const __hip_bfloat16* __restrict__ Vt,
                     __hip_bfloat16* __restrict__ O) {
  __shared__ alignas(16) __hip_bfloat16 kt[64][LDP];
  __shared__ alignas(16) __hip_bfloat16 vtt[DKH][LDP];
  __shared__ alignas(16) __hip_bfloat16 plT[4][32][LDP];

  const int t = threadIdx.x;
  const int lane = t & 63;
  const int w = t >> 6;
  const int h = blockIdx.y;
  const int q0 = blockIdx.x * 128;
  const int col = lane & 15;
  const int quad = lane >> 4;

  bf16x8 qf[2][2];
  #pragma unroll
  for (int rg = 0; rg < 2; ++rg) {
    const __hip_bfloat16* qptr =
        Q + (size_t)(q0 + w * 32 + rg * 16 + col) * DMODEL + h * DKH + quad * 8;
    qf[rg][0] = *(const bf16x8*)qptr;
    qf[rg][1] = *(const bf16x8*)(qptr + 32);
  }

  f32x4 acc_o[2][4] = {};
  float lsumq[2] = {0.f, 0.f};
  const int sr = t >> 2;
  const int sc = (t & 3) * 16;

  for (int k0 = 0; k0 < SEQ; k0 += 64) {
    __syncthreads();
    const __hip_bfloat16* kg = K + (size_t)(k0 + sr) * DMODEL + h * DKH + sc;
    *(bf16x8*)&kt[sr][sc]     = *(const bf16x8*)kg;
    *(bf16x8*)&kt[sr][sc + 8] = *(const bf16x8*)(kg + 8);
    const __hip_bfloat16* vg = Vt + (size_t)(h * DKH + sr) * SEQ + k0 + sc;
    *(bf16x8*)&vtt[sr][sc]     = *(const bf16x8*)vg;
    *(bf16x8*)&vtt[sr][sc + 8] = *(const bf16x8*)(vg + 8);
    __syncthreads();

    #pragma unroll
    for (int jt = 0; jt < 4; ++jt) {
      const bf16x8 kf0 = *(const bf16x8*)&kt[jt * 16 + col][quad * 8];
      const bf16x8 kf1 = *(const bf16x8*)&kt[jt * 16 + col][quad * 8 + 32];
      #pragma unroll
      for (int rg = 0; rg < 2; ++rg) {
        f32x4 zz = {0.f, 0.f, 0.f, 0.f};
        zz = __builtin_amdgcn_mfma_f32_16x16x32_bf16(kf0, qf[rg][0], zz, 0, 0, 0);
        zz = __builtin_amdgcn_mfma_f32_16x16x32_bf16(kf1, qf[rg][1], zz, 0, 0, 0);
        bf16x4 pk;
        #pragma unroll
        for (int r = 0; r < 4; ++r) {
          const float p = __expf(zz[r] - SHIFT);
          lsumq[rg] += p;
          pk[r] = (__bf16)p;
        }
        *(bf16x4*)&plT[w][rg * 16 + col][jt * 16 + quad * 4] = pk;
      }
    }

    bf16x8 pa[2][2];
    #pragma unroll
    for (int rg = 0; rg < 2; ++rg) {
      pa[rg][0] = *(const bf16x8*)&plT[w][rg * 16 + col][quad * 8];
      pa[rg][1] = *(const bf16x8*)&plT[w][rg * 16 + col][quad * 8 + 32];
    }
    #pragma unroll
    for (int jt = 0; jt < 4; ++jt) {
      const bf16x8 vb0 = *(const bf16x8*)&vtt[jt * 16 + col][quad * 8];
      const bf16x8 vb1 = *(const bf16x8*)&vtt[jt * 16 + col][quad * 8 + 32];
      #pragma unroll
      for (int rg = 0; rg < 2; ++rg) {
        acc_o[rg][jt] = __builtin_amdgcn_mfma_f32_16x16x32_bf16(
            pa[rg][0], vb0, acc_o[rg][jt], 0, 0, 0);
        acc_o[rg][jt] = __builtin_amdgcn_mfma_f32_16x16x32_bf16(
            pa[rg][1], vb1, acc_o[rg][jt], 0, 0, 0);
      }
    }
  }

  #pragma unroll
  for (int rg = 0; rg < 2; ++rg) {
    lsumq[rg] += __shfl_xor(lsumq[rg], 16);
    lsumq[rg] += __shfl_xor(lsumq[rg], 32);
  }
  float invr[2][4];
  #pragma unroll
  for (int rg = 0; rg < 2; ++rg)
    #pragma unroll
    for (int r = 0; r < 4; ++r)
      invr[rg][r] = 1.f / __shfl(lsumq[rg], quad * 4 + r);

  #pragma unroll
  for (int rg = 0; rg < 2; ++rg) {
    #pragma unroll
    for (int jt = 0; jt < 4; ++jt) {
      #pragma unroll
      for (int r = 0; r < 4; ++r) {
        const int qr = q0 + w * 32 + rg * 16 + quad * 4 + r;
        const int c = h * DKH + jt * 16 + col;
        O[(size_t)qr * DMODEL + c] = __float2bfloat16(acc_o[rg][jt][r] * invr[rg][r]);
      }
    }
  }
}

// ---------------------------------------------------------------------------
// Interface: inputs fp32 dict-order, output fp32.
// FAST path (ws_size >= 40 MB), 6 dispatches, no memcpy.
//   d_out: Qp [0,8M) | Xq [8,16M) -> Opart2 (z4)   (dead before final write)
//   ws: Kp[0,8) Vt[8,16) | Xk[16,24)->Opart0->Ao | Xv[24,32)->Opart1 |
//       Wqb[32,34)->lsum@33M | Wkb[34,36) Wvb[36,38) Wob[38,40) |
//       [40,48) -> Opart3 (only if ws >= 48 MB; else nz=2)
// ---------------------------------------------------------------------------
extern "C" void kernel_launch(void* const* d_in, const int* in_sizes, int n_in,
                              void* d_out, int out_size, void* d_ws, size_t ws_size,
                              hipStream_t stream) {
  const float* query = (const float*)d_in[0];
  const float* key   = (const float*)d_in[1];
  const float* value = (const float*)d_in[2];
  const float* W_q   = (const float*)d_in[3];
  const float* b_q   = (const float*)d_in[4];
  const float* W_k   = (const float*)d_in[5];
  const float* b_k   = (const float*)d_in[6];
  const float* W_v   = (const float*)d_in[7];
  const float* b_v   = (const float*)d_in[8];
  const float* W_o   = (const float*)d_in[9];
  const float* b_o   = (const float*)d_in[10];

  float* out = (float*)d_out;
  const size_t mat = (size_t)SEQ * DMODEL;
  const size_t MB = 1024 * 1024;

  char* ws = (char*)d_ws;
  __hip_bfloat16* Qp = (__hip_bfloat16*)d_out;            // d_out [0,8M)
  __hip_bfloat16* Kp = (__hip_bfloat16*)ws;               // ws [0,8M)
  __hip_bfloat16* Vt = Kp + mat;                          // ws [8,16M)

  dim3 gblock(256);

  if (ws_size >= 40 * MB) {
    __bf16* Xq  = (__bf16*)((char*)d_out + 8 * MB);
    __bf16* Xk  = (__bf16*)(ws + 16 * MB);
    __bf16* Xv  = (__bf16*)(ws + 24 * MB);
    __bf16* Wqb = (__bf16*)(ws + 32 * MB);
    __bf16* Wkb = (__bf16*)(ws + 34 * MB);
    __bf16* Wvb = (__bf16*)(ws + 36 * MB);
    __bf16* Wob = (__bf16*)(ws + 38 * MB);
    __hip_bfloat16* Op0 = (__hip_bfloat16*)(ws + 16 * MB);
    __hip_bfloat16* Op1 = (__hip_bfloat16*)(ws + 24 * MB);
    __hip_bfloat16* Op2 = (__hip_bfloat16*)((char*)d_out + 8 * MB);  // Xq dead
    __hip_bfloat16* Op3 = (__hip_bfloat16*)(ws + 40 * MB);
    float* lsum = (float*)(ws + 33 * MB);   // up to 1 MB (nz=4); Wqb dead
    __hip_bfloat16* Ao = (__hip_bfloat16*)(ws + 16 * MB);  // combine in place

    const int nz = (ws_size >= 48 * MB) ? 4 : 2;

    hipLaunchKernelGGL(cvt_all, dim3(8192), gblock, 0, stream,
                       query, key, value, W_q, W_k, W_v, W_o,
                       Xq, Xk, Xv, Wqb, Wkb, Wvb, Wob);

    // Fused Q/K/V projections: (16, 32, 3) = 1536 blocks (XCD-swizzled).
    dim3 qkvgrid(DMODEL / 64, SEQ / 128, 3);
    hipLaunchKernelGGL(gemm_qkv, qkvgrid, gblock, 0, stream,
                       Xq, Xk, Xv, Wqb, Wkb, Wvb, b_q, b_k, b_v,
                       Qp, Kp, Vt);

    dim3 agrid(SEQ / 128, NH, nz);  // single flash dispatch (R19 config)
    hipLaunchKernelGGL(flash_attn_splitN, agrid, gblock, 0, stream,
                       Qp, Kp, Vt, Op0, Op1, Op2, Op3, lsum);
    hipLaunchKernelGGL(attn_combine, dim3(2048), gblock, 0, stream,
                       Op0, Op1, Op2, Op3, lsum, Ao, nz);

    dim3 ogrid(DMODEL / 64, SEQ / 128);  // (16, 32) = 512 blocks
    hipLaunchKernelGGL((gemm128<float, false>), ogrid, gblock, 0, stream,
                       (const __bf16*)Ao, Wob, b_o, out, 1.0f);
  } else {
    // fallback: R10-proven plan (16 MB ws)
    __hip_bfloat16* Ao = Qp + mat;         // d_out [8,16M)
    float* Cw = (float*)d_ws;
    dim3 fgrid(DMODEL / 64, SEQ / 128);    // (16, 32) for gemm_tiled
    hipLaunchKernelGGL((gemm_tiled<float, __hip_bfloat16, false>), fgrid, gblock,
                       0, stream, query, W_q, b_q, Qp, SCALE);
    hipLaunchKernelGGL((gemm_tiled<float, __hip_bfloat16, false>), fgrid, gblock,
                       0, stream, key, W_k, b_k, Kp, 1.0f);
    hipLaunchKernelGGL((gemm_tiled<float, __hip_bfloat16, true>), fgrid, gblock,
                       0, stream, value, W_v, b_v, Vt, 1.0f);
    dim3 agrid(SEQ / 128, NH);
    hipLaunchKernelGGL(flash_attn_mono, agrid, gblock, 0, stream, Qp, Kp, Vt, Ao);
    hipLaunchKernelGGL((gemm_tiled<__hip_bfloat16, float, false>), fgrid, gblock,
                       0, stream, Ao, W_o, b_o, Cw, 1.0f);
    hipMemcpyAsync(out, Cw, mat * sizeof(float), hipMemcpyDeviceToDevice, stream);
  }
}